// Round 8
// baseline (236.506 us; speedup 1.0000x reference)
//
#include <hip/hip_runtime.h>
#include <hip/hip_bf16.h>

// MHA: B=2, S=4096, E=512, H=8, D=64. fp32 in/out, bf16 MFMA internally.
// 3 dispatches: qkv (fp32-direct), attn, outproj (fp32-direct).
// ws (shorts): Q | K | VT | O  (4 x 8192*512)
// Q pre-scaled by log2(e)/sqrt(D). attn: S^T via 32x32x16 (col=q=lane&31,
// row t=(reg&3)+8*(reg>>2)+4*(lane>>5)) feeds PV 32x32x8 A-operand
// (k=4*(lane>>5)+j) directly from registers. LDS tiles: 16B-chunk XOR swizzle.

typedef __attribute__((ext_vector_type(8))) short short8;
typedef __attribute__((ext_vector_type(4))) short short4v;
typedef __attribute__((ext_vector_type(4))) float floatx4;
typedef __attribute__((ext_vector_type(2))) float floatx2;
typedef __attribute__((ext_vector_type(16))) float floatx16;

#define SEQ 4096
#define EMB 512
#define NH 8
#define HD 64
#define MROWS 8192
#define SC2 0.18033688011112042f  // log2(e)/sqrt(64)

__device__ inline unsigned short f2bf_rne(float f) {
    union { float f; unsigned int u; } c; c.f = f;
    unsigned int u = c.u;
    return (unsigned short)((u + 0x7FFFu + ((u >> 16) & 1u)) >> 16);
}

__device__ inline void gload_lds16(const void* g, void* l) {
    __builtin_amdgcn_global_load_lds(
        (const __attribute__((address_space(1))) void*)g,
        (__attribute__((address_space(3))) void*)l,
        16, 0, 0);
}

// pack 2 f32 -> 2 bf16 (round-half-up) in one v_perm
__device__ inline unsigned int pk_bf2(float a, float b) {
    union { float f; unsigned int u; } ca, cb; ca.f = a; cb.f = b;
    return __builtin_amdgcn_perm(cb.u + 0x8000u, ca.u + 0x8000u, 0x07060302u);
}

// build bf16x8 frag from 8 fp32 in LDS (two float4 slots)
__device__ inline short8 frag8f(const float* p0, const float* p1) {
    float4 u = *(const float4*)p0;
    float4 v = *(const float4*)p1;
    union { uint4 u4; short8 s8; } cv;
    cv.u4.x = pk_bf2(u.x, u.y); cv.u4.y = pk_bf2(u.z, u.w);
    cv.u4.z = pk_bf2(v.x, v.y); cv.u4.w = pk_bf2(v.z, v.w);
    return cv.s8;
}

// ---------------- QKV projection, fp32-direct, 128x128, BK=64, single-buffer ----------------
// z=0 -> Q [b,h,s,d] scaled SC2; z=1 -> K [b,h,s,d]; z=2 -> V^T [b,h,d,s]
__global__ __launch_bounds__(256) void qkv_kernel(
    const float* __restrict__ X, const float* __restrict__ Wq,
    const float* __restrict__ Wk, const float* __restrict__ Wv,
    const float* __restrict__ bq, const float* __restrict__ bk,
    const float* __restrict__ bv, unsigned short* __restrict__ Qo,
    unsigned short* __restrict__ Ko, unsigned short* __restrict__ VTo)
{
    __shared__ float fs[16384];  // fsA[8192]=128x64 f32 | fsB[8192]; epilogue ct aliases
    float* fsA = fs;
    float* fsB = fs + 8192;

    const int tid = threadIdx.x, wave = tid >> 6, lane = tid & 63;
    const int quad = lane >> 4, l16 = lane & 15;
    const int wm = wave >> 1, wn = wave & 1;
    const int row0 = blockIdx.x * 128, col0 = blockIdx.y * 128;
    const int z = blockIdx.z;

    const float* A = X + (size_t)row0 * EMB;
    const float* W = z == 0 ? Wq : z == 1 ? Wk : Wv;
    const float* Bm = W + (size_t)col0 * EMB;
    const float* bias = z == 0 ? bq : z == 1 ? bk : bv;
    unsigned short* out = z == 0 ? Qo : z == 1 ? Ko : VTo;

    floatx4 acc[4][4];
#pragma unroll
    for (int i = 0; i < 4; ++i)
#pragma unroll
        for (int j = 0; j < 4; ++j) { floatx4 zz = {0.f,0.f,0.f,0.f}; acc[i][j] = zz; }

    for (int k0 = 0; k0 < EMB; k0 += 64) {
        __syncthreads();
        // stage fp32 tiles: 128 rows x 16 chunks (16B=4 floats), XOR-swizzled
#pragma unroll
        for (int it = 0; it < 8; ++it) {
            const int s = it * 256 + tid;
            const int row = s >> 4, c = (s & 15) ^ (row & 7);
            gload_lds16(A + (size_t)row * EMB + k0 + c * 4, &fsA[(it * 256 + wave * 64) * 4]);
            gload_lds16(Bm + (size_t)row * EMB + k0 + c * 4, &fsB[(it * 256 + wave * 64) * 4]);
        }
        __syncthreads();
#pragma unroll
        for (int kk = 0; kk < 2; ++kk) {
            short8 a[4], b[4];
#pragma unroll
            for (int mi = 0; mi < 4; ++mi) {
                const int row = wm * 64 + mi * 16 + l16, rm = row & 7;
                const int c0 = kk * 8 + 2 * quad;
                a[mi] = frag8f(&fsA[row * 64 + ((c0 ^ rm) << 2)],
                               &fsA[row * 64 + (((c0 + 1) ^ rm) << 2)]);
            }
#pragma unroll
            for (int ni = 0; ni < 4; ++ni) {
                const int row = wn * 64 + ni * 16 + l16, rm = row & 7;
                const int c0 = kk * 8 + 2 * quad;
                b[ni] = frag8f(&fsB[row * 64 + ((c0 ^ rm) << 2)],
                               &fsB[row * 64 + (((c0 + 1) ^ rm) << 2)]);
            }
            if (z != 2) {
#pragma unroll
                for (int i = 0; i < 4; ++i)
#pragma unroll
                    for (int j = 0; j < 4; ++j)
                        acc[i][j] = __builtin_amdgcn_mfma_f32_16x16x32_bf16(b[i], a[j], acc[i][j], 0, 0, 0);
            } else {
#pragma unroll
                for (int i = 0; i < 4; ++i)
#pragma unroll
                    for (int j = 0; j < 4; ++j)
                        acc[i][j] = __builtin_amdgcn_mfma_f32_16x16x32_bf16(a[i], b[j], acc[i][j], 0, 0, 0);
            }
        }
    }

    // ---- epilogue: pack b64 into ct[row][132] then coalesced b128 stores ----
    __syncthreads();
    unsigned short* ct = (unsigned short*)fs;  // 128 x 132 shorts = 33.8 KB
    const float qs = (z == 0) ? SC2 : 1.0f;
    if (z != 2) {
#pragma unroll
        for (int i = 0; i < 4; ++i) {
            const int n0 = wn * 64 + i * 16 + quad * 4;
            const float4 fb = *(const float4*)&bias[col0 + n0];
#pragma unroll
            for (int j = 0; j < 4; ++j) {
                const int m = wm * 64 + j * 16 + l16;
                ushort4 pk;
                pk.x = f2bf_rne((acc[i][j][0] + fb.x) * qs);
                pk.y = f2bf_rne((acc[i][j][1] + fb.y) * qs);
                pk.z = f2bf_rne((acc[i][j][2] + fb.z) * qs);
                pk.w = f2bf_rne((acc[i][j][3] + fb.w) * qs);
                *(ushort4*)&ct[m * 132 + n0] = pk;
            }
        }
    } else {
#pragma unroll
        for (int j = 0; j < 4; ++j) {
            const int n = wn * 64 + j * 16 + l16;
            const float fb = bias[col0 + n];
#pragma unroll
            for (int i = 0; i < 4; ++i) {
                const int m0 = wm * 64 + i * 16 + quad * 4;
                ushort4 pk;
                pk.x = f2bf_rne(acc[i][j][0] + fb);
                pk.y = f2bf_rne(acc[i][j][1] + fb);
                pk.z = f2bf_rne(acc[i][j][2] + fb);
                pk.w = f2bf_rne(acc[i][j][3] + fb);
                *(ushort4*)&ct[n * 132 + m0] = pk;
            }
        }
    }
    __syncthreads();
#pragma unroll
    for (int it = 0; it < 8; ++it) {
        const int idx = it * 256 + tid;
        const int row = idx >> 4, chunk = idx & 15;
        short8 v = *(const short8*)&ct[row * 132 + chunk * 8];
        size_t addr;
        if (z != 2) {
            const int m_g = row0 + row;
            const int b = m_g >> 12, s = m_g & 4095;
            const int n_g = col0 + chunk * 8;
            const int h = n_g >> 6, d = n_g & 63;
            addr = ((size_t)((b * NH + h) * SEQ + s)) * HD + d;
        } else {
            const int n_g = col0 + row;
            const int h = n_g >> 6, d = n_g & 63;
            const int m_g = row0 + chunk * 8;
            const int b = m_g >> 12, s0 = m_g & 4095;
            addr = ((size_t)((b * NH + h) * HD + d)) * SEQ + s0;
        }
        *(short8*)&out[addr] = v;
    }
}

// ---------------- flash attention: 32x32 QK + register-direct 32x32x8 PV ----------------
__global__ __launch_bounds__(256) void attn_kernel(
    const unsigned short* __restrict__ Q, const unsigned short* __restrict__ K,
    const unsigned short* __restrict__ VT, unsigned short* __restrict__ Oout)
{
    __shared__ unsigned short sK[2][4096];   // 64 t x 64 d (swizzled)
    __shared__ unsigned short sVT[2][4096];  // 64 d x 64 t (swizzled)

    const int tid = threadIdx.x, wave = tid >> 6, lane = tid & 63;
    const int l32 = lane & 31, hi = lane >> 5;
    const int bh = blockIdx.x, q0 = blockIdx.y * 128;

    const unsigned short* Qh = Q + (size_t)bh * SEQ * HD;
    const unsigned short* Kh = K + (size_t)bh * SEQ * HD;
    const unsigned short* Vh = VT + (size_t)bh * HD * SEQ;

    // Q as 32x32x16 B-operand: lane = q(l32) + 32*b(hi), k = hi*8+j -> d = kk*16+hi*8+j
    short8 qf[4];
#pragma unroll
    for (int kk = 0; kk < 4; ++kk)
        qf[kk] = *(const short8*)(Qh + (size_t)(q0 + wave * 32 + l32) * HD + kk * 16 + hi * 8);

    const floatx16 z16 = {0.f,0.f,0.f,0.f,0.f,0.f,0.f,0.f,0.f,0.f,0.f,0.f,0.f,0.f,0.f,0.f};
    floatx16 oacc[2];
    oacc[0] = z16; oacc[1] = z16;
    floatx2 psum2 = {0.f, 0.f};

    auto stage = [&](int buf, int t0) {
#pragma unroll
        for (int psi = 0; psi < 2; ++psi) {
            const int r = psi * 32 + wave * 8 + (lane >> 3);
            const int c = (lane & 7) ^ (r & 7);
            gload_lds16(Kh + (size_t)(t0 + r) * HD + c * 8, &sK[buf][psi * 2048 + wave * 512]);
            gload_lds16(Vh + (size_t)r * SEQ + t0 + c * 8, &sVT[buf][psi * 2048 + wave * 512]);
        }
    };

    stage(0, 0);
    int buf = 0;
    for (int t0 = 0; t0 < SEQ; t0 += 64) {
        __syncthreads();
        if (t0 + 64 < SEQ) stage(buf ^ 1, t0 + 64);

        // S^T = K Q^T per 32-t half: A = K-frag (m=t, k=d), B = qf
        floatx16 stf[2];
#pragma unroll
        for (int th = 0; th < 2; ++th) {
            const int row = th * 32 + l32, rm = l32 & 7;
            short8 aK = *(const short8*)&sK[buf][row * 64 + (((0 * 2 + hi) ^ rm) << 3)];
            stf[th] = __builtin_amdgcn_mfma_f32_32x32x16_bf16(aK, qf[0], z16, 0, 0, 0);
#pragma unroll
            for (int kk = 1; kk < 4; ++kk) {
                aK = *(const short8*)&sK[buf][row * 64 + (((kk * 2 + hi) ^ rm) << 3)];
                stf[th] = __builtin_amdgcn_mfma_f32_32x32x16_bf16(aK, qf[kk], stf[th], 0, 0, 0);
            }
        }

        // exp2 -> pack PV A-frags in registers (C rows t=(j)+8s+4hi == A k=4hi+j per slice s)
        short4v paf[2][4];
#pragma unroll
        for (int th = 0; th < 2; ++th)
#pragma unroll
            for (int s = 0; s < 4; ++s) {
                const float p0 = __builtin_amdgcn_exp2f(stf[th][4 * s + 0]);
                const float p1 = __builtin_amdgcn_exp2f(stf[th][4 * s + 1]);
                const float p2 = __builtin_amdgcn_exp2f(stf[th][4 * s + 2]);
                const float p3 = __builtin_amdgcn_exp2f(stf[th][4 * s + 3]);
                floatx2 pa = {p0, p1}, pb = {p2, p3};
                psum2 += pa + pb;
                union { uint2 u; short4v s4; } cv;
                cv.u.x = pk_bf2(p0, p1);
                cv.u.y = pk_bf2(p2, p3);
                paf[th][s] = cv.s4;
            }

        // O += P V via 32x32x8: A = paf (m=q, k=t), B = V^T b64 (n=d, k=t)
#pragma unroll
        for (int dh = 0; dh < 2; ++dh) {
            const int row = dh * 32 + l32, rm = l32 & 7;
#pragma unroll
            for (int th = 0; th < 2; ++th)
#pragma unroll
                for (int s = 0; s < 4; ++s) {
                    short4v bv = *(const short4v*)&sVT[buf][row * 64 +
                                 (((th * 4 + s) ^ rm) << 3) + hi * 4];
                    oacc[dh] = __builtin_amdgcn_mfma_f32_32x32x8bf16_1k(paf[th][s], bv, oacc[dh], 0, 0, 0);
                }
        }
        buf ^= 1;
    }

    // psum(q) lives at lanes l32==q in both hi halves; reduce across hi
    float psum = psum2[0] + psum2[1];
    psum += __shfl_xor(psum, 32);
    const float inv = 1.0f / psum;

    const int b = bh >> 3, h = bh & 7;
#pragma unroll
    for (int dh = 0; dh < 2; ++dh)
#pragma unroll
        for (int rr = 0; rr < 4; ++rr)
#pragma unroll
            for (int j = 0; j < 4; ++j) {
                const int qrow = j + 8 * rr + 4 * hi;
                const float v = oacc[dh][rr * 4 + j] * __shfl(inv, qrow);
                const int s = q0 + wave * 32 + qrow;
                const int d = dh * 32 + l32;
                Oout[((size_t)b * SEQ + s) * EMB + h * HD + d] = f2bf_rne(v);
            }
}

// ---------------- output projection: O(bf16) x Wo(fp32-direct) + bo + x ----------------
__global__ __launch_bounds__(256) void outproj_kernel(
    const unsigned short* __restrict__ Ain, const float* __restrict__ Wo,
    const float* __restrict__ bias, const float* __restrict__ X,
    float* __restrict__ out)
{
    __shared__ unsigned short osA[4096];  // 64 x 64 bf16
    __shared__ float ofsB[8192];          // 128 x 64 f32

    const int tid = threadIdx.x, wave = tid >> 6, lane = tid & 63;
    const int quad = lane >> 4, l16 = lane & 15;
    const int wm = wave >> 1, wn = wave & 1;
    const int row0 = blockIdx.x * 64, col0 = blockIdx.y * 128;

    const unsigned short* A = Ain + (size_t)row0 * EMB;
    const float* Bm = Wo + (size_t)col0 * EMB;

    floatx4 acc[2][4];
#pragma unroll
    for (int mi = 0; mi < 2; ++mi)
#pragma unroll
        for (int ni = 0; ni < 4; ++ni) { floatx4 zz = {0.f,0.f,0.f,0.f}; acc[mi][ni] = zz; }

    for (int k0 = 0; k0 < EMB; k0 += 64) {
        __syncthreads();
#pragma unroll
        for (int it = 0; it < 2; ++it) {
            const int s = it * 256 + tid;
            const int row = s >> 3, c = (s & 7) ^ (row & 7);
            gload_lds16(A + (size_t)row * EMB + k0 + c * 8, &osA[(it * 256 + wave * 64) * 8]);
        }
#pragma unroll
        for (int it = 0; it < 8; ++it) {
            const int s = it * 256 + tid;
            const int row = s >> 4, c = (s & 15) ^ (row & 7);
            gload_lds16(Bm + (size_t)row * EMB + k0 + c * 4, &ofsB[(it * 256 + wave * 64) * 4]);
        }
        __syncthreads();
#pragma unroll
        for (int kk = 0; kk < 2; ++kk) {
            short8 a[2], b[4];
#pragma unroll
            for (int mi = 0; mi < 2; ++mi) {
                const int row = wm * 32 + mi * 16 + l16;
                a[mi] = *(const short8*)&osA[row * 64 + (((kk * 4 + quad) ^ (row & 7)) << 3)];
            }
#pragma unroll
            for (int ni = 0; ni < 4; ++ni) {
                const int row = wn * 64 + ni * 16 + l16, rm = row & 7;
                const int c0 = kk * 8 + 2 * quad;
                b[ni] = frag8f(&ofsB[row * 64 + ((c0 ^ rm) << 2)],
                               &ofsB[row * 64 + (((c0 + 1) ^ rm) << 2)]);
            }
#pragma unroll
            for (int mi = 0; mi < 2; ++mi)
#pragma unroll
                for (int ni = 0; ni < 4; ++ni)
                    acc[mi][ni] = __builtin_amdgcn_mfma_f32_16x16x32_bf16(a[mi], b[ni], acc[mi][ni], 0, 0, 0);
        }
    }

#pragma unroll
    for (int mi = 0; mi < 2; ++mi)
#pragma unroll
        for (int ni = 0; ni < 4; ++ni) {
            const int n = col0 + wn * 64 + ni * 16 + l16;
            const float bs = bias[n];
#pragma unroll
            for (int r = 0; r < 4; ++r) {
                const int m = row0 + wm * 32 + mi * 16 + quad * 4 + r;
                const size_t idx = (size_t)m * EMB + n;
                out[idx] = acc[mi][ni][r] + bs + X[idx];
            }
        }
}

extern "C" void kernel_launch(void* const* d_in, const int* in_sizes, int n_in,
                              void* d_out, int out_size, void* d_ws, size_t ws_size,
                              hipStream_t stream) {
    const float* x  = (const float*)d_in[0];
    const float* Wq = (const float*)d_in[1];
    const float* bq = (const float*)d_in[2];
    const float* Wk = (const float*)d_in[3];
    const float* bk = (const float*)d_in[4];
    const float* Wv = (const float*)d_in[5];
    const float* bv = (const float*)d_in[6];
    const float* Wo = (const float*)d_in[7];
    const float* bo = (const float*)d_in[8];
    float* out = (float*)d_out;

    const size_t SZ = (size_t)MROWS * EMB;
    unsigned short* wsQ  = (unsigned short*)d_ws;
    unsigned short* wsK  = wsQ + SZ;
    unsigned short* wsVT = wsK + SZ;
    unsigned short* wsO  = wsVT + SZ;

    qkv_kernel<<<dim3(MROWS / 128, EMB / 128, 3), 256, 0, stream>>>(
        x, Wq, Wk, Wv, bq, bk, bv, wsQ, wsK, wsVT);
    attn_kernel<<<dim3(2 * NH, SEQ / 128), 256, 0, stream>>>(wsQ, wsK, wsVT, wsO);
    outproj_kernel<<<dim3(MROWS / 64, EMB / 128), 256, 0, stream>>>(
        wsO, Wo, bo, x, out);
}

// Round 9
// 204.841 us; speedup vs baseline: 1.1546x; 1.1546x over previous
//
#include <hip/hip_runtime.h>
#include <hip/hip_bf16.h>

// MHA: B=2, S=4096, E=512, H=8, D=64. fp32 in/out, bf16 MFMA internally.
// ws (shorts): XB/O [8192*512] | WB [4*512*512] | Q | K | VT
// Q pre-scaled by log2(e)/sqrt(D). attn computes S^T = mfma(K,Q); its C-layout
// (col=q=l16, rows t=quad*4+r) IS the A-operand layout of 16x16x16 MFMA, so
// exp2(P) feeds PV directly from registers (no LDS round-trip).
// attn round 9: 128 t per barrier (2x 64-t sub-tiles, double-buffered) to halve
// barrier-drain lockstep. LDS tiles: 16B-chunk XOR swizzle c ^= (row&7).

typedef __attribute__((ext_vector_type(8))) short short8;
typedef __attribute__((ext_vector_type(4))) short short4v;
typedef __attribute__((ext_vector_type(4))) float floatx4;
typedef __attribute__((ext_vector_type(2))) float floatx2;

#define SEQ 4096
#define EMB 512
#define NH 8
#define HD 64
#define MROWS 8192
#define SC2 0.18033688011112042f  // log2(e)/sqrt(64)

__device__ inline unsigned short f2bf_rne(float f) {
    union { float f; unsigned int u; } c; c.f = f;
    unsigned int u = c.u;
    return (unsigned short)((u + 0x7FFFu + ((u >> 16) & 1u)) >> 16);
}

__device__ inline short8 load8f(const float* __restrict__ p) {
    float4 a = *(const float4*)p;
    float4 b = *(const float4*)(p + 4);
    short8 r;
    r[0] = (short)f2bf_rne(a.x); r[1] = (short)f2bf_rne(a.y);
    r[2] = (short)f2bf_rne(a.z); r[3] = (short)f2bf_rne(a.w);
    r[4] = (short)f2bf_rne(b.x); r[5] = (short)f2bf_rne(b.y);
    r[6] = (short)f2bf_rne(b.z); r[7] = (short)f2bf_rne(b.w);
    return r;
}

__device__ inline void gload_lds16(const unsigned short* g, unsigned short* l) {
    __builtin_amdgcn_global_load_lds(
        (__attribute__((address_space(1))) void*)(void*)g,
        (__attribute__((address_space(3))) void*)l,
        16, 0, 0);
}

// pack 2 f32 -> 2 bf16 (round-half-up) in one v_perm
__device__ inline unsigned int pk_bf2(float a, float b) {
    union { float f; unsigned int u; } ca, cb; ca.f = a; cb.f = b;
    return __builtin_amdgcn_perm(cb.u + 0x8000u, ca.u + 0x8000u, 0x07060302u);
}

// ---------------- fp32 -> bf16 pre-convert ----------------
__global__ __launch_bounds__(256) void convert_kernel(
    const float* __restrict__ x, const float* __restrict__ Wq,
    const float* __restrict__ Wk, const float* __restrict__ Wv,
    const float* __restrict__ Wo, unsigned short* __restrict__ xb,
    unsigned short* __restrict__ wb)
{
    const size_t i8 = ((size_t)blockIdx.x * 256 + threadIdx.x) * 8;
    const float* src; unsigned short* dst;
    if (i8 < (size_t)MROWS * EMB) { src = x + i8; dst = xb + i8; }
    else {
        size_t j = i8 - (size_t)MROWS * EMB;
        int w = (int)(j >> 18); size_t off = j & 262143;
        src = (w == 0 ? Wq : w == 1 ? Wk : w == 2 ? Wv : Wo) + off;
        dst = wb + (size_t)w * 262144 + off;
    }
    *(short8*)dst = load8f(src);
}

// ---------------- QKV projection, 128x128, BK=64, dbuf, LDS epilogue ----------------
// z=0 -> Q [b,h,s,d] scaled SC2; z=1 -> K [b,h,s,d]; z=2 -> V^T [b,h,d,s]
__global__ __launch_bounds__(256) void qkv_kernel(
    const unsigned short* __restrict__ xb, const unsigned short* __restrict__ wb,
    const float* __restrict__ bq, const float* __restrict__ bk,
    const float* __restrict__ bv, unsigned short* __restrict__ Qo,
    unsigned short* __restrict__ Ko, unsigned short* __restrict__ VTo)
{
    __shared__ unsigned short smem[32768];  // sA[2][8192] | sB[2][8192]; epilogue ct aliases

    const int tid = threadIdx.x, wave = tid >> 6, lane = tid & 63;
    const int quad = lane >> 4, l16 = lane & 15;
    const int wm = wave >> 1, wn = wave & 1;
    const int row0 = blockIdx.x * 128, col0 = blockIdx.y * 128;
    const int z = blockIdx.z;

    unsigned short* sA = smem;
    unsigned short* sB = smem + 16384;

    const unsigned short* A = xb + (size_t)row0 * EMB;
    const unsigned short* Bm = wb + (size_t)z * 262144 + (size_t)col0 * EMB;
    const float* bias = z == 0 ? bq : z == 1 ? bk : bv;
    unsigned short* out = z == 0 ? Qo : z == 1 ? Ko : VTo;

    auto stage = [&](int buf, int k0) {
#pragma unroll
        for (int it = 0; it < 4; ++it) {
            const int s = it * 256 + tid;
            const int row = s >> 3, cg = (s & 7) ^ (row & 7);
            const size_t go = (size_t)row * EMB + k0 + cg * 8;
            gload_lds16(A + go, &sA[buf * 8192 + (it * 256 + wave * 64) * 8]);
            gload_lds16(Bm + go, &sB[buf * 8192 + (it * 256 + wave * 64) * 8]);
        }
    };

    floatx4 acc[4][4];
#pragma unroll
    for (int i = 0; i < 4; ++i)
#pragma unroll
        for (int j = 0; j < 4; ++j) { floatx4 zz = {0.f,0.f,0.f,0.f}; acc[i][j] = zz; }

    stage(0, 0);
    int buf = 0;
    for (int k0 = 0; k0 < EMB; k0 += 64) {
        __syncthreads();
        if (k0 + 64 < EMB) stage(buf ^ 1, k0 + 64);
#pragma unroll
        for (int kk = 0; kk < 2; ++kk) {
            short8 a[4], b[4];
#pragma unroll
            for (int mi = 0; mi < 4; ++mi)
                a[mi] = *(const short8*)&sA[buf * 8192 + (wm * 64 + mi * 16 + l16) * 64 + (((kk * 4 + quad) ^ (l16 & 7)) << 3)];
#pragma unroll
            for (int ni = 0; ni < 4; ++ni)
                b[ni] = *(const short8*)&sB[buf * 8192 + (wn * 64 + ni * 16 + l16) * 64 + (((kk * 4 + quad) ^ (l16 & 7)) << 3)];
            if (z != 2) {
                // swapped operands -> acc[i][j] = C^T block: rows n (i), cols m (j)
#pragma unroll
                for (int i = 0; i < 4; ++i)
#pragma unroll
                    for (int j = 0; j < 4; ++j)
                        acc[i][j] = __builtin_amdgcn_mfma_f32_16x16x32_bf16(b[i], a[j], acc[i][j], 0, 0, 0);
            } else {
#pragma unroll
                for (int i = 0; i < 4; ++i)
#pragma unroll
                    for (int j = 0; j < 4; ++j)
                        acc[i][j] = __builtin_amdgcn_mfma_f32_16x16x32_bf16(a[i], b[j], acc[i][j], 0, 0, 0);
            }
        }
        buf ^= 1;
    }

    // ---- epilogue: pack b64 into ct[row][132] then coalesced b128 stores ----
    __syncthreads();
    unsigned short* ct = smem;  // 128 x 132 shorts = 33.8 KB (aliases staging)
    const float qs = (z == 0) ? SC2 : 1.0f;
    if (z != 2) {
#pragma unroll
        for (int i = 0; i < 4; ++i) {
            const int n0 = wn * 64 + i * 16 + quad * 4;
            const float4 fb = *(const float4*)&bias[col0 + n0];
#pragma unroll
            for (int j = 0; j < 4; ++j) {
                const int m = wm * 64 + j * 16 + l16;
                ushort4 pk;
                pk.x = f2bf_rne((acc[i][j][0] + fb.x) * qs);
                pk.y = f2bf_rne((acc[i][j][1] + fb.y) * qs);
                pk.z = f2bf_rne((acc[i][j][2] + fb.z) * qs);
                pk.w = f2bf_rne((acc[i][j][3] + fb.w) * qs);
                *(ushort4*)&ct[m * 132 + n0] = pk;
            }
        }
    } else {
#pragma unroll
        for (int j = 0; j < 4; ++j) {
            const int n = wn * 64 + j * 16 + l16;
            const float fb = bias[col0 + n];
#pragma unroll
            for (int i = 0; i < 4; ++i) {
                const int m0 = wm * 64 + i * 16 + quad * 4;
                ushort4 pk;
                pk.x = f2bf_rne(acc[i][j][0] + fb);
                pk.y = f2bf_rne(acc[i][j][1] + fb);
                pk.z = f2bf_rne(acc[i][j][2] + fb);
                pk.w = f2bf_rne(acc[i][j][3] + fb);
                *(ushort4*)&ct[n * 132 + m0] = pk;
            }
        }
    }
    __syncthreads();
#pragma unroll
    for (int it = 0; it < 8; ++it) {
        const int idx = it * 256 + tid;
        const int row = idx >> 4, chunk = idx & 15;
        short8 v = *(const short8*)&ct[row * 132 + chunk * 8];
        size_t addr;
        if (z != 2) {
            const int m_g = row0 + row;
            const int b = m_g >> 12, s = m_g & 4095;
            const int n_g = col0 + chunk * 8;
            const int h = n_g >> 6, d = n_g & 63;
            addr = ((size_t)((b * NH + h) * SEQ + s)) * HD + d;
        } else {
            const int n_g = col0 + row;
            const int h = n_g >> 6, d = n_g & 63;
            const int m_g = row0 + chunk * 8;
            const int b = m_g >> 12, s0 = m_g & 4095;
            addr = ((size_t)((b * NH + h) * HD + d)) * SEQ + s0;
        }
        *(short8*)&out[addr] = v;
    }
}

// ---------------- flash attention: register P-frags, 16x16x16 PV, 128-t per barrier ----------------
// grid (bh, q-tile): same-bh blocks land on same XCD (stride 16 % 8 == 0) -> L2 reuse
__global__ __launch_bounds__(256) void attn_kernel(
    const unsigned short* __restrict__ Q, const unsigned short* __restrict__ K,
    const unsigned short* __restrict__ VT, unsigned short* __restrict__ Oout)
{
    __shared__ unsigned short sK[2][2][4096];   // [buf][sub] 64 t x 64 d (swizzled)
    __shared__ unsigned short sVT[2][2][4096];  // [buf][sub] 64 d x 64 t (swizzled)

    const int tid = threadIdx.x, wave = tid >> 6, lane = tid & 63;
    const int quad = lane >> 4, l16 = lane & 15;
    const int bh = blockIdx.x, q0 = blockIdx.y * 128;

    const unsigned short* Qh = Q + (size_t)bh * SEQ * HD;
    const unsigned short* Kh = K + (size_t)bh * SEQ * HD;
    const unsigned short* Vh = VT + (size_t)bh * HD * SEQ;

    short8 qf[2][2];
#pragma unroll
    for (int mi = 0; mi < 2; ++mi)
#pragma unroll
        for (int kk = 0; kk < 2; ++kk)
            qf[mi][kk] = *(const short8*)(Qh + (size_t)(q0 + wave * 32 + mi * 16 + l16) * HD + kk * 32 + quad * 8);

    floatx4 oacc[2][4];
#pragma unroll
    for (int mi = 0; mi < 2; ++mi)
#pragma unroll
        for (int dt = 0; dt < 4; ++dt) { floatx4 zz = {0.f,0.f,0.f,0.f}; oacc[mi][dt] = zz; }
    floatx2 psum2[2] = {{0.f, 0.f}, {0.f, 0.f}};

    // stage 128 t (two 64-t sub-tiles) into buffer `buf`
    auto stage = [&](int buf, int t0) {
#pragma unroll
        for (int sub = 0; sub < 2; ++sub)
#pragma unroll
            for (int psi = 0; psi < 2; ++psi) {
                const int r = psi * 32 + wave * 8 + (lane >> 3);
                const int c = (lane & 7) ^ (r & 7);
                gload_lds16(Kh + (size_t)(t0 + sub * 64 + r) * HD + c * 8,
                            &sK[buf][sub][psi * 2048 + wave * 512]);
                gload_lds16(Vh + (size_t)r * SEQ + t0 + sub * 64 + c * 8,
                            &sVT[buf][sub][psi * 2048 + wave * 512]);
            }
    };

    stage(0, 0);
    int buf = 0;
    for (int t0 = 0; t0 < SEQ; t0 += 128) {
        __syncthreads();
        if (t0 + 128 < SEQ) stage(buf ^ 1, t0 + 128);

#pragma unroll
        for (int sub = 0; sub < 2; ++sub) {
            const unsigned short* sKs  = sK[buf][sub];
            const unsigned short* sVTs = sVT[buf][sub];

            // S^T = K Q^T (Q pre-scaled: already log2-domain)
            floatx4 stf[2][4];
#pragma unroll
            for (int mi = 0; mi < 2; ++mi)
#pragma unroll
                for (int nt = 0; nt < 4; ++nt) { floatx4 zz = {0.f,0.f,0.f,0.f}; stf[mi][nt] = zz; }
#pragma unroll
            for (int kk = 0; kk < 2; ++kk) {
                short8 bK[4];
#pragma unroll
                for (int nt = 0; nt < 4; ++nt)
                    bK[nt] = *(const short8*)&sKs[(nt * 16 + l16) * 64 + (((kk * 4 + quad) ^ (l16 & 7)) << 3)];
#pragma unroll
                for (int mi = 0; mi < 2; ++mi)
#pragma unroll
                    for (int nt = 0; nt < 4; ++nt)
                        stf[mi][nt] = __builtin_amdgcn_mfma_f32_16x16x32_bf16(bK[nt], qf[mi][kk], stf[mi][nt], 0, 0, 0);
            }

            // exp2 -> pack A-frags in registers (S^T C-layout == 16x16x16 A-layout)
            short4v paf[2][4];
#pragma unroll
            for (int mi = 0; mi < 2; ++mi)
#pragma unroll
                for (int nt = 0; nt < 4; ++nt) {
                    const float p0 = __builtin_amdgcn_exp2f(stf[mi][nt][0]);
                    const float p1 = __builtin_amdgcn_exp2f(stf[mi][nt][1]);
                    const float p2 = __builtin_amdgcn_exp2f(stf[mi][nt][2]);
                    const float p3 = __builtin_amdgcn_exp2f(stf[mi][nt][3]);
                    floatx2 a = {p0, p1}, b = {p2, p3};
                    psum2[mi] += a + b;
                    union { uint2 u; short4v s; } cv;
                    cv.u.x = pk_bf2(p0, p1);
                    cv.u.y = pk_bf2(p2, p3);
                    paf[mi][nt] = cv.s;
                }

            // O += P V via 16x16x16: A from regs, B = V b64 swizzled reads
#pragma unroll
            for (int nt = 0; nt < 4; ++nt) {
                short4v bv[4];
#pragma unroll
                for (int dt = 0; dt < 4; ++dt)
                    bv[dt] = *(const short4v*)&sVTs[(dt * 16 + l16) * 64 +
                             (((nt * 2 + (quad >> 1)) ^ (l16 & 7)) << 3) + (quad & 1) * 4];
#pragma unroll
                for (int mi = 0; mi < 2; ++mi)
#pragma unroll
                    for (int dt = 0; dt < 4; ++dt)
                        oacc[mi][dt] = __builtin_amdgcn_mfma_f32_16x16x16bf16_1k(paf[mi][nt], bv[dt], oacc[mi][dt], 0, 0, 0);
            }
        }
        buf ^= 1;
    }

    // reduce psum across quad-groups (same l16 holds same q)
    float psum[2];
#pragma unroll
    for (int mi = 0; mi < 2; ++mi) {
        psum[mi] = psum2[mi][0] + psum2[mi][1];
        psum[mi] += __shfl_xor(psum[mi], 16);
        psum[mi] += __shfl_xor(psum[mi], 32);
    }

    const int b = bh >> 3, h = bh & 7;
#pragma unroll
    for (int mi = 0; mi < 2; ++mi)
#pragma unroll
        for (int r = 0; r < 4; ++r) {
            const float inv = 1.0f / __shfl(psum[mi], quad * 4 + r);
            const int s = q0 + wave * 32 + mi * 16 + quad * 4 + r;
            const size_t base = ((size_t)b * SEQ + s) * EMB + h * HD;
#pragma unroll
            for (int dt = 0; dt < 4; ++dt)
                Oout[base + dt * 16 + l16] = f2bf_rne(oacc[mi][dt][r] * inv);
        }
}

// ---------------- output projection, 64x128 tile, double-buffered ----------------
__global__ __launch_bounds__(256) void outproj_kernel(
    const unsigned short* __restrict__ Ain, const unsigned short* __restrict__ wob,
    const float* __restrict__ bias, const float* __restrict__ X,
    float* __restrict__ out)
{
    __shared__ unsigned short sA[2][4096];
    __shared__ unsigned short sB[2][8192];

    const int tid = threadIdx.x, wave = tid >> 6, lane = tid & 63;
    const int quad = lane >> 4, l16 = lane & 15;
    const int wm = wave >> 1, wn = wave & 1;
    const int row0 = blockIdx.x * 64, col0 = blockIdx.y * 128;

    const unsigned short* A = Ain + (size_t)row0 * EMB;
    const unsigned short* Bm = wob + (size_t)col0 * EMB;

    auto stage = [&](int buf, int k0) {
#pragma unroll
        for (int it = 0; it < 2; ++it) {
            const int s = it * 256 + tid;
            const int row = s >> 3, cg = (s & 7) ^ (row & 7);
            gload_lds16(A + (size_t)row * EMB + k0 + cg * 8, &sA[buf][(it * 256 + wave * 64) * 8]);
        }
#pragma unroll
        for (int it = 0; it < 4; ++it) {
            const int s = it * 256 + tid;
            const int row = s >> 3, cg = (s & 7) ^ (row & 7);
            gload_lds16(Bm + (size_t)row * EMB + k0 + cg * 8, &sB[buf][(it * 256 + wave * 64) * 8]);
        }
    };

    floatx4 acc[2][4];
#pragma unroll
    for (int mi = 0; mi < 2; ++mi)
#pragma unroll
        for (int ni = 0; ni < 4; ++ni) { floatx4 zz = {0.f,0.f,0.f,0.f}; acc[mi][ni] = zz; }

    stage(0, 0);
    int buf = 0;
    for (int k0 = 0; k0 < EMB; k0 += 64) {
        __syncthreads();
        if (k0 + 64 < EMB) stage(buf ^ 1, k0 + 64);
#pragma unroll
        for (int kk = 0; kk < 2; ++kk) {
            short8 a[2], b[4];
#pragma unroll
            for (int mi = 0; mi < 2; ++mi)
                a[mi] = *(const short8*)&sA[buf][(wm * 32 + mi * 16 + l16) * 64 + (((kk * 4 + quad) ^ (l16 & 7)) << 3)];
#pragma unroll
            for (int ni = 0; ni < 4; ++ni)
                b[ni] = *(const short8*)&sB[buf][(wn * 64 + ni * 16 + l16) * 64 + (((kk * 4 + quad) ^ (l16 & 7)) << 3)];
#pragma unroll
            for (int mi = 0; mi < 2; ++mi)
#pragma unroll
                for (int ni = 0; ni < 4; ++ni)
                    acc[mi][ni] = __builtin_amdgcn_mfma_f32_16x16x32_bf16(a[mi], b[ni], acc[mi][ni], 0, 0, 0);
        }
        buf ^= 1;
    }

#pragma unroll
    for (int mi = 0; mi < 2; ++mi)
#pragma unroll
        for (int ni = 0; ni < 4; ++ni) {
            const int n = col0 + wn * 64 + ni * 16 + l16;
            const float bs = bias[n];
#pragma unroll
            for (int r = 0; r < 4; ++r) {
                const int m = row0 + wm * 32 + mi * 16 + quad * 4 + r;
                const size_t idx = (size_t)m * EMB + n;
                out[idx] = acc[mi][ni][r] + bs + X[idx];
            }
        }
}

extern "C" void kernel_launch(void* const* d_in, const int* in_sizes, int n_in,
                              void* d_out, int out_size, void* d_ws, size_t ws_size,
                              hipStream_t stream) {
    const float* x  = (const float*)d_in[0];
    const float* Wq = (const float*)d_in[1];
    const float* bq = (const float*)d_in[2];
    const float* Wk = (const float*)d_in[3];
    const float* bk = (const float*)d_in[4];
    const float* Wv = (const float*)d_in[5];
    const float* bv = (const float*)d_in[6];
    const float* Wo = (const float*)d_in[7];
    const float* bo = (const float*)d_in[8];
    float* out = (float*)d_out;

    const size_t SZ = (size_t)MROWS * EMB;
    unsigned short* wsXB = (unsigned short*)d_ws;  // also O (attn output)
    unsigned short* wsWB = wsXB + SZ;
    unsigned short* wsQ  = wsWB + 4 * 262144;
    unsigned short* wsK  = wsQ + SZ;
    unsigned short* wsVT = wsK + SZ;

    convert_kernel<<<2560, 256, 0, stream>>>(x, Wq, Wk, Wv, Wo, wsXB, wsWB);
    qkv_kernel<<<dim3(MROWS / 128, EMB / 128, 3), 256, 0, stream>>>(
        wsXB, wsWB, bq, bk, bv, wsQ, wsK, wsVT);
    attn_kernel<<<dim3(2 * NH, SEQ / 128), 256, 0, stream>>>(wsQ, wsK, wsVT, wsXB);
    outproj_kernel<<<dim3(MROWS / 64, EMB / 128), 256, 0, stream>>>(
        wsXB, wsWB + 3 * 262144, bo, x, out);
}

// Round 10
// 199.414 us; speedup vs baseline: 1.1860x; 1.0272x over previous
//
#include <hip/hip_runtime.h>
#include <hip/hip_bf16.h>

// MHA: B=2, S=4096, E=512, H=8, D=64. fp32 in/out, bf16 MFMA internally.
// ws (shorts): XB/O [8192*512] | WB [4*512*512] | Q | K | VT
// Q pre-scaled by log2(e)/sqrt(D). attn computes S^T = mfma(K,Q); its C-layout
// (col=q=l16, rows t=quad*4+r) IS the A-operand layout of 16x16x16 MFMA, so
// exp2(P) feeds PV directly from registers (no LDS round-trip).
// attn r10 VALU diet: const-zero C on first QK MFMA (no stf zero-init movs),
// truncating bf16 P-pack (1 v_perm per 2 vals; psum stays fp32-exact).
// LDS tiles: 16B-chunk XOR swizzle c ^= (row&7).

typedef __attribute__((ext_vector_type(8))) short short8;
typedef __attribute__((ext_vector_type(4))) short short4v;
typedef __attribute__((ext_vector_type(4))) float floatx4;
typedef __attribute__((ext_vector_type(2))) float floatx2;

#define SEQ 4096
#define EMB 512
#define NH 8
#define HD 64
#define MROWS 8192
#define SC2 0.18033688011112042f  // log2(e)/sqrt(64)

__device__ inline unsigned short f2bf_rne(float f) {
    union { float f; unsigned int u; } c; c.f = f;
    unsigned int u = c.u;
    return (unsigned short)((u + 0x7FFFu + ((u >> 16) & 1u)) >> 16);
}

__device__ inline short8 load8f(const float* __restrict__ p) {
    float4 a = *(const float4*)p;
    float4 b = *(const float4*)(p + 4);
    short8 r;
    r[0] = (short)f2bf_rne(a.x); r[1] = (short)f2bf_rne(a.y);
    r[2] = (short)f2bf_rne(a.z); r[3] = (short)f2bf_rne(a.w);
    r[4] = (short)f2bf_rne(b.x); r[5] = (short)f2bf_rne(b.y);
    r[6] = (short)f2bf_rne(b.z); r[7] = (short)f2bf_rne(b.w);
    return r;
}

__device__ inline void gload_lds16(const unsigned short* g, unsigned short* l) {
    __builtin_amdgcn_global_load_lds(
        (__attribute__((address_space(1))) void*)(void*)g,
        (__attribute__((address_space(3))) void*)l,
        16, 0, 0);
}

// pack 2 f32 -> 2 bf16, round-half-up (epilogue-quality)
__device__ inline unsigned int pk_bf2(float a, float b) {
    union { float f; unsigned int u; } ca, cb; ca.f = a; cb.f = b;
    return __builtin_amdgcn_perm(cb.u + 0x8000u, ca.u + 0x8000u, 0x07060302u);
}

// pack 2 f32 -> 2 bf16, truncating (P-matrix: positive values, <=0.2% bias)
__device__ inline unsigned int pk_bf2t(float a, float b) {
    union { float f; unsigned int u; } ca, cb; ca.f = a; cb.f = b;
    return __builtin_amdgcn_perm(cb.u, ca.u, 0x07060302u);
}

// ---------------- fp32 -> bf16 pre-convert ----------------
__global__ __launch_bounds__(256) void convert_kernel(
    const float* __restrict__ x, const float* __restrict__ Wq,
    const float* __restrict__ Wk, const float* __restrict__ Wv,
    const float* __restrict__ Wo, unsigned short* __restrict__ xb,
    unsigned short* __restrict__ wb)
{
    const size_t i8 = ((size_t)blockIdx.x * 256 + threadIdx.x) * 8;
    const float* src; unsigned short* dst;
    if (i8 < (size_t)MROWS * EMB) { src = x + i8; dst = xb + i8; }
    else {
        size_t j = i8 - (size_t)MROWS * EMB;
        int w = (int)(j >> 18); size_t off = j & 262143;
        src = (w == 0 ? Wq : w == 1 ? Wk : w == 2 ? Wv : Wo) + off;
        dst = wb + (size_t)w * 262144 + off;
    }
    *(short8*)dst = load8f(src);
}

// ---------------- QKV projection, 128x128, BK=64, dbuf, LDS epilogue ----------------
// z=0 -> Q [b,h,s,d] scaled SC2; z=1 -> K [b,h,s,d]; z=2 -> V^T [b,h,d,s]
__global__ __launch_bounds__(256) void qkv_kernel(
    const unsigned short* __restrict__ xb, const unsigned short* __restrict__ wb,
    const float* __restrict__ bq, const float* __restrict__ bk,
    const float* __restrict__ bv, unsigned short* __restrict__ Qo,
    unsigned short* __restrict__ Ko, unsigned short* __restrict__ VTo)
{
    __shared__ unsigned short smem[32768];  // sA[2][8192] | sB[2][8192]; epilogue ct aliases

    const int tid = threadIdx.x, wave = tid >> 6, lane = tid & 63;
    const int quad = lane >> 4, l16 = lane & 15;
    const int wm = wave >> 1, wn = wave & 1;
    const int row0 = blockIdx.x * 128, col0 = blockIdx.y * 128;
    const int z = blockIdx.z;

    unsigned short* sA = smem;
    unsigned short* sB = smem + 16384;

    const unsigned short* A = xb + (size_t)row0 * EMB;
    const unsigned short* Bm = wb + (size_t)z * 262144 + (size_t)col0 * EMB;
    const float* bias = z == 0 ? bq : z == 1 ? bk : bv;
    unsigned short* out = z == 0 ? Qo : z == 1 ? Ko : VTo;

    auto stage = [&](int buf, int k0) {
#pragma unroll
        for (int it = 0; it < 4; ++it) {
            const int s = it * 256 + tid;
            const int row = s >> 3, cg = (s & 7) ^ (row & 7);
            const size_t go = (size_t)row * EMB + k0 + cg * 8;
            gload_lds16(A + go, &sA[buf * 8192 + (it * 256 + wave * 64) * 8]);
            gload_lds16(Bm + go, &sB[buf * 8192 + (it * 256 + wave * 64) * 8]);
        }
    };

    floatx4 acc[4][4];
#pragma unroll
    for (int i = 0; i < 4; ++i)
#pragma unroll
        for (int j = 0; j < 4; ++j) { floatx4 zz = {0.f,0.f,0.f,0.f}; acc[i][j] = zz; }

    stage(0, 0);
    int buf = 0;
    for (int k0 = 0; k0 < EMB; k0 += 64) {
        __syncthreads();
        if (k0 + 64 < EMB) stage(buf ^ 1, k0 + 64);
#pragma unroll
        for (int kk = 0; kk < 2; ++kk) {
            short8 a[4], b[4];
#pragma unroll
            for (int mi = 0; mi < 4; ++mi)
                a[mi] = *(const short8*)&sA[buf * 8192 + (wm * 64 + mi * 16 + l16) * 64 + (((kk * 4 + quad) ^ (l16 & 7)) << 3)];
#pragma unroll
            for (int ni = 0; ni < 4; ++ni)
                b[ni] = *(const short8*)&sB[buf * 8192 + (wn * 64 + ni * 16 + l16) * 64 + (((kk * 4 + quad) ^ (l16 & 7)) << 3)];
            if (z != 2) {
                // swapped operands -> acc[i][j] = C^T block: rows n (i), cols m (j)
#pragma unroll
                for (int i = 0; i < 4; ++i)
#pragma unroll
                    for (int j = 0; j < 4; ++j)
                        acc[i][j] = __builtin_amdgcn_mfma_f32_16x16x32_bf16(b[i], a[j], acc[i][j], 0, 0, 0);
            } else {
#pragma unroll
                for (int i = 0; i < 4; ++i)
#pragma unroll
                    for (int j = 0; j < 4; ++j)
                        acc[i][j] = __builtin_amdgcn_mfma_f32_16x16x32_bf16(a[i], b[j], acc[i][j], 0, 0, 0);
            }
        }
        buf ^= 1;
    }

    // ---- epilogue: pack b64 into ct[row][132] then coalesced b128 stores ----
    __syncthreads();
    unsigned short* ct = smem;  // 128 x 132 shorts = 33.8 KB (aliases staging)
    const float qs = (z == 0) ? SC2 : 1.0f;
    if (z != 2) {
#pragma unroll
        for (int i = 0; i < 4; ++i) {
            const int n0 = wn * 64 + i * 16 + quad * 4;
            const float4 fb = *(const float4*)&bias[col0 + n0];
#pragma unroll
            for (int j = 0; j < 4; ++j) {
                const int m = wm * 64 + j * 16 + l16;
                ushort4 pk;
                pk.x = f2bf_rne((acc[i][j][0] + fb.x) * qs);
                pk.y = f2bf_rne((acc[i][j][1] + fb.y) * qs);
                pk.z = f2bf_rne((acc[i][j][2] + fb.z) * qs);
                pk.w = f2bf_rne((acc[i][j][3] + fb.w) * qs);
                *(ushort4*)&ct[m * 132 + n0] = pk;
            }
        }
    } else {
#pragma unroll
        for (int j = 0; j < 4; ++j) {
            const int n = wn * 64 + j * 16 + l16;
            const float fb = bias[col0 + n];
#pragma unroll
            for (int i = 0; i < 4; ++i) {
                const int m0 = wm * 64 + i * 16 + quad * 4;
                ushort4 pk;
                pk.x = f2bf_rne(acc[i][j][0] + fb);
                pk.y = f2bf_rne(acc[i][j][1] + fb);
                pk.z = f2bf_rne(acc[i][j][2] + fb);
                pk.w = f2bf_rne(acc[i][j][3] + fb);
                *(ushort4*)&ct[n * 132 + m0] = pk;
            }
        }
    }
    __syncthreads();
#pragma unroll
    for (int it = 0; it < 8; ++it) {
        const int idx = it * 256 + tid;
        const int row = idx >> 4, chunk = idx & 15;
        short8 v = *(const short8*)&ct[row * 132 + chunk * 8];
        size_t addr;
        if (z != 2) {
            const int m_g = row0 + row;
            const int b = m_g >> 12, s = m_g & 4095;
            const int n_g = col0 + chunk * 8;
            const int h = n_g >> 6, d = n_g & 63;
            addr = ((size_t)((b * NH + h) * SEQ + s)) * HD + d;
        } else {
            const int n_g = col0 + row;
            const int h = n_g >> 6, d = n_g & 63;
            const int m_g = row0 + chunk * 8;
            const int b = m_g >> 12, s0 = m_g & 4095;
            addr = ((size_t)((b * NH + h) * HD + d)) * SEQ + s0;
        }
        *(short8*)&out[addr] = v;
    }
}

// ---------------- flash attention: register P-frags, 16x16x16 PV, 128-t per barrier ----------------
// grid (bh, q-tile): same-bh blocks land on same XCD (stride 16 % 8 == 0) -> L2 reuse
__global__ __launch_bounds__(256) void attn_kernel(
    const unsigned short* __restrict__ Q, const unsigned short* __restrict__ K,
    const unsigned short* __restrict__ VT, unsigned short* __restrict__ Oout)
{
    __shared__ unsigned short sK[2][2][4096];   // [buf][sub] 64 t x 64 d (swizzled)
    __shared__ unsigned short sVT[2][2][4096];  // [buf][sub] 64 d x 64 t (swizzled)

    const int tid = threadIdx.x, wave = tid >> 6, lane = tid & 63;
    const int quad = lane >> 4, l16 = lane & 15;
    const int bh = blockIdx.x, q0 = blockIdx.y * 128;
    const int xm = l16 & 7;  // xor swizzle mask for this lane's rows

    const unsigned short* Qh = Q + (size_t)bh * SEQ * HD;
    const unsigned short* Kh = K + (size_t)bh * SEQ * HD;
    const unsigned short* Vh = VT + (size_t)bh * HD * SEQ;

    short8 qf[2][2];
#pragma unroll
    for (int mi = 0; mi < 2; ++mi)
#pragma unroll
        for (int kk = 0; kk < 2; ++kk)
            qf[mi][kk] = *(const short8*)(Qh + (size_t)(q0 + wave * 32 + mi * 16 + l16) * HD + kk * 32 + quad * 8);

    floatx4 oacc[2][4];
#pragma unroll
    for (int mi = 0; mi < 2; ++mi)
#pragma unroll
        for (int dt = 0; dt < 4; ++dt) { floatx4 zz = {0.f,0.f,0.f,0.f}; oacc[mi][dt] = zz; }
    floatx2 psum2[2] = {{0.f, 0.f}, {0.f, 0.f}};
    const floatx4 z4 = {0.f, 0.f, 0.f, 0.f};

    // stage 128 t (two 64-t sub-tiles) into buffer `buf`
    auto stage = [&](int buf, int t0) {
#pragma unroll
        for (int sub = 0; sub < 2; ++sub)
#pragma unroll
            for (int psi = 0; psi < 2; ++psi) {
                const int r = psi * 32 + wave * 8 + (lane >> 3);
                const int c = (lane & 7) ^ (r & 7);
                gload_lds16(Kh + (size_t)(t0 + sub * 64 + r) * HD + c * 8,
                            &sK[buf][sub][psi * 2048 + wave * 512]);
                gload_lds16(Vh + (size_t)r * SEQ + t0 + sub * 64 + c * 8,
                            &sVT[buf][sub][psi * 2048 + wave * 512]);
            }
    };

    stage(0, 0);
    int buf = 0;
    for (int t0 = 0; t0 < SEQ; t0 += 128) {
        __syncthreads();
        if (t0 + 128 < SEQ) stage(buf ^ 1, t0 + 128);

#pragma unroll
        for (int sub = 0; sub < 2; ++sub) {
            const unsigned short* sKs  = sK[buf][sub];
            const unsigned short* sVTs = sVT[buf][sub];

            // S^T = K Q^T (Q pre-scaled: already log2-domain).
            // kk=0 uses constant-zero C (no accumulator zero-init movs).
            floatx4 stf[2][4];
            {
                short8 bK[4];
#pragma unroll
                for (int nt = 0; nt < 4; ++nt)
                    bK[nt] = *(const short8*)&sKs[(nt * 16 + l16) * 64 + ((quad ^ xm) << 3)];
#pragma unroll
                for (int mi = 0; mi < 2; ++mi)
#pragma unroll
                    for (int nt = 0; nt < 4; ++nt)
                        stf[mi][nt] = __builtin_amdgcn_mfma_f32_16x16x32_bf16(bK[nt], qf[mi][0], z4, 0, 0, 0);
            }
            {
                short8 bK[4];
#pragma unroll
                for (int nt = 0; nt < 4; ++nt)
                    bK[nt] = *(const short8*)&sKs[(nt * 16 + l16) * 64 + (((4 + quad) ^ xm) << 3)];
#pragma unroll
                for (int mi = 0; mi < 2; ++mi)
#pragma unroll
                    for (int nt = 0; nt < 4; ++nt)
                        stf[mi][nt] = __builtin_amdgcn_mfma_f32_16x16x32_bf16(bK[nt], qf[mi][1], stf[mi][nt], 0, 0, 0);
            }

            // exp2 -> truncating pack into A-frags (S^T C-layout == 16x16x16 A-layout);
            // psum accumulated on pre-pack fp32 values (denominator exact)
            short4v paf[2][4];
#pragma unroll
            for (int mi = 0; mi < 2; ++mi)
#pragma unroll
                for (int nt = 0; nt < 4; ++nt) {
                    const float p0 = __builtin_amdgcn_exp2f(stf[mi][nt][0]);
                    const float p1 = __builtin_amdgcn_exp2f(stf[mi][nt][1]);
                    const float p2 = __builtin_amdgcn_exp2f(stf[mi][nt][2]);
                    const float p3 = __builtin_amdgcn_exp2f(stf[mi][nt][3]);
                    floatx2 a = {p0, p1}, b = {p2, p3};
                    psum2[mi] += a + b;
                    union { uint2 u; short4v s; } cv;
                    cv.u.x = pk_bf2t(p0, p1);
                    cv.u.y = pk_bf2t(p2, p3);
                    paf[mi][nt] = cv.s;
                }

            // O += P V via 16x16x16: A from regs, B = V b64 swizzled reads
#pragma unroll
            for (int nt = 0; nt < 4; ++nt) {
                short4v bv[4];
#pragma unroll
                for (int dt = 0; dt < 4; ++dt)
                    bv[dt] = *(const short4v*)&sVTs[(dt * 16 + l16) * 64 +
                             (((nt * 2 + (quad >> 1)) ^ xm) << 3) + (quad & 1) * 4];
#pragma unroll
                for (int mi = 0; mi < 2; ++mi)
#pragma unroll
                    for (int dt = 0; dt < 4; ++dt)
                        oacc[mi][dt] = __builtin_amdgcn_mfma_f32_16x16x16bf16_1k(paf[mi][nt], bv[dt], oacc[mi][dt], 0, 0, 0);
            }
        }
        buf ^= 1;
    }

    // reduce psum across quad-groups (same l16 holds same q)
    float psum[2];
#pragma unroll
    for (int mi = 0; mi < 2; ++mi) {
        psum[mi] = psum2[mi][0] + psum2[mi][1];
        psum[mi] += __shfl_xor(psum[mi], 16);
        psum[mi] += __shfl_xor(psum[mi], 32);
    }

    const int b = bh >> 3, h = bh & 7;
#pragma unroll
    for (int mi = 0; mi < 2; ++mi)
#pragma unroll
        for (int r = 0; r < 4; ++r) {
            const float inv = 1.0f / __shfl(psum[mi], quad * 4 + r);
            const int s = q0 + wave * 32 + mi * 16 + quad * 4 + r;
            const size_t base = ((size_t)b * SEQ + s) * EMB + h * HD;
#pragma unroll
            for (int dt = 0; dt < 4; ++dt)
                Oout[base + dt * 16 + l16] = f2bf_rne(oacc[mi][dt][r] * inv);
        }
}

// ---------------- output projection, 64x128 tile, double-buffered ----------------
__global__ __launch_bounds__(256) void outproj_kernel(
    const unsigned short* __restrict__ Ain, const unsigned short* __restrict__ wob,
    const float* __restrict__ bias, const float* __restrict__ X,
    float* __restrict__ out)
{
    __shared__ unsigned short sA[2][4096];
    __shared__ unsigned short sB[2][8192];

    const int tid = threadIdx.x, wave = tid >> 6, lane = tid & 63;
    const int quad = lane >> 4, l16 = lane & 15;
    const int wm = wave >> 1, wn = wave & 1;
    const int row0 = blockIdx.x * 64, col0 = blockIdx.y * 128;

    const unsigned short* A = Ain + (size_t)row0 * EMB;
    const unsigned short* Bm = wob + (size_t)col0 * EMB;

    auto stage = [&](int buf, int k0) {
#pragma unroll
        for (int it = 0; it < 2; ++it) {
            const int s = it * 256 + tid;
            const int row = s >> 3, cg = (s & 7) ^ (row & 7);
            gload_lds16(A + (size_t)row * EMB + k0 + cg * 8, &sA[buf][(it * 256 + wave * 64) * 8]);
        }
#pragma unroll
        for (int it = 0; it < 4; ++it) {
            const int s = it * 256 + tid;
            const int row = s >> 3, cg = (s & 7) ^ (row & 7);
            gload_lds16(Bm + (size_t)row * EMB + k0 + cg * 8, &sB[buf][(it * 256 + wave * 64) * 8]);
        }
    };

    floatx4 acc[2][4];
#pragma unroll
    for (int mi = 0; mi < 2; ++mi)
#pragma unroll
        for (int ni = 0; ni < 4; ++ni) { floatx4 zz = {0.f,0.f,0.f,0.f}; acc[mi][ni] = zz; }

    stage(0, 0);
    int buf = 0;
    for (int k0 = 0; k0 < EMB; k0 += 64) {
        __syncthreads();
        if (k0 + 64 < EMB) stage(buf ^ 1, k0 + 64);
#pragma unroll
        for (int kk = 0; kk < 2; ++kk) {
            short8 a[2], b[4];
#pragma unroll
            for (int mi = 0; mi < 2; ++mi)
                a[mi] = *(const short8*)&sA[buf][(wm * 32 + mi * 16 + l16) * 64 + (((kk * 4 + quad) ^ (l16 & 7)) << 3)];
#pragma unroll
            for (int ni = 0; ni < 4; ++ni)
                b[ni] = *(const short8*)&sB[buf][(wn * 64 + ni * 16 + l16) * 64 + (((kk * 4 + quad) ^ (l16 & 7)) << 3)];
#pragma unroll
            for (int mi = 0; mi < 2; ++mi)
#pragma unroll
                for (int ni = 0; ni < 4; ++ni)
                    acc[mi][ni] = __builtin_amdgcn_mfma_f32_16x16x32_bf16(a[mi], b[ni], acc[mi][ni], 0, 0, 0);
        }
        buf ^= 1;
    }

#pragma unroll
    for (int mi = 0; mi < 2; ++mi)
#pragma unroll
        for (int ni = 0; ni < 4; ++ni) {
            const int n = col0 + wn * 64 + ni * 16 + l16;
            const float bs = bias[n];
#pragma unroll
            for (int r = 0; r < 4; ++r) {
                const int m = row0 + wm * 32 + mi * 16 + quad * 4 + r;
                const size_t idx = (size_t)m * EMB + n;
                out[idx] = acc[mi][ni][r] + bs + X[idx];
            }
        }
}

extern "C" void kernel_launch(void* const* d_in, const int* in_sizes, int n_in,
                              void* d_out, int out_size, void* d_ws, size_t ws_size,
                              hipStream_t stream) {
    const float* x  = (const float*)d_in[0];
    const float* Wq = (const float*)d_in[1];
    const float* bq = (const float*)d_in[2];
    const float* Wk = (const float*)d_in[3];
    const float* bk = (const float*)d_in[4];
    const float* Wv = (const float*)d_in[5];
    const float* bv = (const float*)d_in[6];
    const float* Wo = (const float*)d_in[7];
    const float* bo = (const float*)d_in[8];
    float* out = (float*)d_out;

    const size_t SZ = (size_t)MROWS * EMB;
    unsigned short* wsXB = (unsigned short*)d_ws;  // also O (attn output)
    unsigned short* wsWB = wsXB + SZ;
    unsigned short* wsQ  = wsWB + 4 * 262144;
    unsigned short* wsK  = wsQ + SZ;
    unsigned short* wsVT = wsK + SZ;

    convert_kernel<<<2560, 256, 0, stream>>>(x, Wq, Wk, Wv, Wo, wsXB, wsWB);
    qkv_kernel<<<dim3(MROWS / 128, EMB / 128, 3), 256, 0, stream>>>(
        wsXB, wsWB, bq, bk, bv, wsQ, wsK, wsVT);
    attn_kernel<<<dim3(2 * NH, SEQ / 128), 256, 0, stream>>>(wsQ, wsK, wsVT, wsXB);
    outproj_kernel<<<dim3(MROWS / 64, EMB / 128), 256, 0, stream>>>(
        wsXB, wsWB + 3 * 262144, bo, x, out);
}